// Round 4
// baseline (8641.088 us; speedup 1.0000x reference)
//
#include <hip/hip_runtime.h>

// B=32, N=100, K=20, D=4096, DI=DO=H=512, 4H=2048, M=B*N=3200
// ws layout (floats): z 13107200 | zW 1638400 | xl 3276800 | gin 6553600
//                     s1 3200 | s2 3200 | vb 512 | h0_all 1638400 | h1_all 1638400
//                     flags (ints) 51200
// Recurrence: ONE persistent kernel, 512 blocks co-resident (LDS 36.9KB -> 4/CU cap),
// per-step producer flags with agent-scope release/acquire; c-state in registers.

#define NSTEP 100

__device__ __forceinline__ float sigf(float x) { return 1.0f / (1.0f + __expf(-x)); }
__device__ __forceinline__ int ld_acq(const int* p) {
  return __hip_atomic_load(p, __ATOMIC_ACQUIRE, __HIP_MEMORY_SCOPE_AGENT);
}
__device__ __forceinline__ void st_rel(int* p, int v) {
  __hip_atomic_store(p, v, __ATOMIC_RELEASE, __HIP_MEMORY_SCOPE_AGENT);
}

// ---------------- Kernel 1: obj_mask (-> alphas), z = sum_k m_k^2 x_k, s1, s2 ----
__global__ __launch_bounds__(256) void mask_z_kernel(
    const float* __restrict__ x, float* __restrict__ z,
    float* __restrict__ s1, float* __restrict__ s2, float* __restrict__ alphas)
{
  int m = blockIdx.x;            // 0..3199
  int b = m / 100, n = m % 100;
  int t = threadIdx.x;           // 256
  const float* xb = x + (size_t)m * 81920;   // x[b,n,0,0]
  __shared__ float red[4];
  float zv[16];
#pragma unroll
  for (int i = 0; i < 16; ++i) zv[i] = 0.f;
  float s1v = 0.f, s2v = 0.f;
  for (int k = 1; k < 20; ++k) {
    const float4* row = (const float4*)(xb + (size_t)k * 4096);
    float4 v0 = row[t], v1 = row[t + 256], v2 = row[t + 512], v3 = row[t + 768];
    float ps = v0.x + v0.y + v0.z + v0.w + v1.x + v1.y + v1.z + v1.w
             + v2.x + v2.y + v2.z + v2.w + v3.x + v3.y + v3.z + v3.w;
#pragma unroll
    for (int off = 32; off >= 1; off >>= 1) ps += __shfl_down(ps, off);
    if ((t & 63) == 0) red[t >> 6] = ps;
    __syncthreads();
    float mk = red[0] + red[1] + red[2] + red[3];
    __syncthreads();
    float mk2 = mk * mk;
    s1v += mk; s2v += mk2;
    if (t == 0) alphas[((size_t)n * 32 + (size_t)b) * 19 + (k - 1)] = mk;
    zv[0] += mk2 * v0.x; zv[1] += mk2 * v0.y; zv[2] += mk2 * v0.z; zv[3] += mk2 * v0.w;
    zv[4] += mk2 * v1.x; zv[5] += mk2 * v1.y; zv[6] += mk2 * v1.z; zv[7] += mk2 * v1.w;
    zv[8] += mk2 * v2.x; zv[9] += mk2 * v2.y; zv[10] += mk2 * v2.z; zv[11] += mk2 * v2.w;
    zv[12] += mk2 * v3.x; zv[13] += mk2 * v3.y; zv[14] += mk2 * v3.z; zv[15] += mk2 * v3.w;
  }
  float4* zr = (float4*)(z + (size_t)m * 4096);
  zr[t]       = make_float4(zv[0], zv[1], zv[2], zv[3]);
  zr[t + 256] = make_float4(zv[4], zv[5], zv[6], zv[7]);
  zr[t + 512] = make_float4(zv[8], zv[9], zv[10], zv[11]);
  zr[t + 768] = make_float4(zv[12], zv[13], zv[14], zv[15]);
  if (t == 0) { s1[m] = s1v; s2[m] = s2v; }
}

// ---------------- tiny: vb[j] = sum_i W_obj2[j,i] * b_obj[i] --------------------
__global__ void colvec_kernel(const float* __restrict__ W2,
                              const float* __restrict__ bo, float* __restrict__ vb)
{
  int j = blockIdx.x * 256 + threadIdx.x;
  if (j < 512) {
    float s = 0.f;
    for (int i = 0; i < 512; ++i) s += W2[(size_t)j * 512 + i] * bo[i];
    vb[j] = s;
  }
}

// ---------------- fp32 GEMM (R2 version, best measured) ------------------------
// BM=64, BN=64, BK=32, 256 threads, 4x4 per thread. K-major LDS, pitch 76.
__global__ __launch_bounds__(256) void gemm_atb(
    const float* __restrict__ A, int lda,
    const float* __restrict__ W, int K,
    float* __restrict__ C, int ldc,
    const float* __restrict__ bias1, const float* __restrict__ bias2,
    const float* __restrict__ rs1, const float* __restrict__ cv1,
    const float* __restrict__ rs2, const float* __restrict__ cv2)
{
  __shared__ __align__(16) float As[32 * 76];
  __shared__ __align__(16) float Ws[32 * 76];
  int t = threadIdx.x;
  int m0 = blockIdx.x * 64, n0 = blockIdx.y * 64;
  int sr = t >> 3;           // 0..31 staging row
  int sc = t & 7;            // 0..7 float4 slot along K
  int r0 = (t >> 4) * 4, c0 = (t & 15) * 4;

  float acc[4][4];
#pragma unroll
  for (int i = 0; i < 4; ++i)
#pragma unroll
    for (int j = 0; j < 4; ++j) acc[i][j] = 0.f;

  const float* Ap0 = A + (size_t)(m0 + sr) * lda + sc * 4;
  const float* Ap1 = A + (size_t)(m0 + sr + 32) * lda + sc * 4;
  const float* Wp0 = W + (size_t)(n0 + sr) * K + sc * 4;
  const float* Wp1 = W + (size_t)(n0 + sr + 32) * K + sc * 4;

  float4 a0 = *(const float4*)(Ap0);
  float4 a1 = *(const float4*)(Ap1);
  float4 w0 = *(const float4*)(Wp0);
  float4 w1 = *(const float4*)(Wp1);

  for (int k0 = 0; k0 < K; k0 += 32) {
    int kb = sc * 4;
#pragma unroll
    for (int j = 0; j < 4; ++j) {
      float aj0 = (j == 0) ? a0.x : (j == 1) ? a0.y : (j == 2) ? a0.z : a0.w;
      float aj1 = (j == 0) ? a1.x : (j == 1) ? a1.y : (j == 2) ? a1.z : a1.w;
      float wj0 = (j == 0) ? w0.x : (j == 1) ? w0.y : (j == 2) ? w0.z : w0.w;
      float wj1 = (j == 0) ? w1.x : (j == 1) ? w1.y : (j == 2) ? w1.z : w1.w;
      As[(kb + j) * 76 + sr]      = aj0;
      As[(kb + j) * 76 + sr + 32] = aj1;
      Ws[(kb + j) * 76 + sr]      = wj0;
      Ws[(kb + j) * 76 + sr + 32] = wj1;
    }
    __syncthreads();
    if (k0 + 32 < K) {
      a0 = *(const float4*)(Ap0 + k0 + 32);
      a1 = *(const float4*)(Ap1 + k0 + 32);
      w0 = *(const float4*)(Wp0 + k0 + 32);
      w1 = *(const float4*)(Wp1 + k0 + 32);
    }
#pragma unroll 8
    for (int kk = 0; kk < 32; ++kk) {
      float4 av = *(const float4*)&As[kk * 76 + r0];
      float4 wv = *(const float4*)&Ws[kk * 76 + c0];
      float ar[4] = {av.x, av.y, av.z, av.w};
      float wr[4] = {wv.x, wv.y, wv.z, wv.w};
#pragma unroll
      for (int i = 0; i < 4; ++i)
#pragma unroll
        for (int j = 0; j < 4; ++j) acc[i][j] += ar[i] * wr[j];
    }
    __syncthreads();
  }
#pragma unroll
  for (int i = 0; i < 4; ++i) {
    int m = m0 + r0 + i;
    float r1v = rs1 ? rs1[m] : 0.f;
    float r2v = rs2 ? rs2[m] : 0.f;
#pragma unroll
    for (int j = 0; j < 4; ++j) {
      int n = n0 + c0 + j;
      float v = acc[i][j];
      if (bias1) v += bias1[n];
      if (bias2) v += bias2[n];
      if (cv1) v += r1v * cv1[n];
      if (cv2) v += r2v * cv2[n];
      C[(size_t)m * ldc + n] = v;
    }
  }
}

// ---------------- Persistent LSTM recurrence ----------------------------------
// grid 512 x 256. bid<256: layer0 unit-pair wg=bid; bid>=256: layer1 unit-pair.
// Step p: A computes h0[p] from h0[p-1]+gin; B computes h1[p] from [h0[p];h1[p-1]].
// Sync: per-producer flags, release-store by producer, acquire-poll by consumer
// (one flag per thread + __syncthreads_and => no atomic-RMW serialization).
// Acyclic dependency DAG + full co-residency => no deadlock.
__global__ __launch_bounds__(256) void lstm_persist(
    const float* __restrict__ gin,
    const float* __restrict__ Whh0,
    const float* __restrict__ Wih1,
    const float* __restrict__ Whh1,
    const float* __restrict__ b_ih1, const float* __restrict__ b_hh1,
    const float* __restrict__ Wout, const float* __restrict__ bout,
    float* __restrict__ h0_all, float* __restrict__ h1_all,
    int* __restrict__ flags0, int* __restrict__ flags1,
    float* __restrict__ preds)
{
  __shared__ __align__(16) float lds[8 * 1024 + 1024];
  int bid = blockIdx.x, t = threadIdx.x;
  bool isA = bid < 256;
  int wg = isA ? bid : bid - 256;

  // ---- stage weight slice into LDS once (XOR(k4,row) swizzle, conflict-free b128)
  {
    int r = t >> 5, c = t & 31;
    int grow = (r >> 1) * 512 + wg * 2 + (r & 1);    // gate-major global row
    if (isA) {
      const float4* src = (const float4*)(Whh0 + (size_t)grow * 512);
#pragma unroll
      for (int i = 0; i < 4; ++i) {
        int k4 = i * 32 + c;
        *(float4*)&lds[r * 512 + ((k4 ^ r) << 2)] = src[k4];
      }
    } else {
      const float4* sih = (const float4*)(Wih1 + (size_t)grow * 512);
      const float4* shh = (const float4*)(Whh1 + (size_t)grow * 512);
#pragma unroll
      for (int i = 0; i < 8; ++i) {
        int k4g = i * 32 + c;
        int half = k4g >> 7;
        int k4 = k4g & 127;
        float4 v = half ? shh[k4] : sih[k4];
        *(float4*)&lds[r * 1024 + half * 512 + ((k4 ^ r) << 2)] = v;
      }
    }
  }
  __syncthreads();

  int tc = t & 7, bg = (t >> 3) & 7, ks = t >> 6;
  int b0 = bg * 4;
  float c_reg = 0.f;   // cell state for (t<64): unit u=t&1, batch b=t>>1

  for (int p = 0; p < NSTEP; ++p) {
    // ---- wait for dependencies
    if (isA) {
      if (p > 0) {
        const int* f = flags0 + (size_t)(p - 1) * 256;
        while (!__syncthreads_and(ld_acq(&f[t]) != 0)) __builtin_amdgcn_s_sleep(8);
      }
    } else {
      const int* f0 = flags0 + (size_t)p * 256;
      const int* f1 = flags1 + (size_t)(p - 1) * 256;   // only read if p>0
      for (;;) {
        int ok = (ld_acq(&f0[t]) != 0) && (p == 0 || ld_acq(&f1[t]) != 0);
        if (__syncthreads_and(ok)) break;
        __builtin_amdgcn_s_sleep(8);
      }
      // B0 additionally emits pred[p-1] (h1[p-1] is complete per flags just acquired)
      if (bid == 256 && p > 0) {
        const float* hp_ = h1_all + (size_t)(p - 1) * 16384;
        float* sc = lds + 8192;
        int b = t & 31, k8 = t >> 5;
        const float* hh = hp_ + b * 512 + k8 * 64;
        const float* wp = Wout + k8 * 64;
        float s = 0.f;
#pragma unroll
        for (int i = 0; i < 64; ++i) s += hh[i] * wp[i];
        sc[k8 * 32 + b] = s;
        __syncthreads();
        if (t < 32) {
          float acc = bout[0];
#pragma unroll
          for (int k8i = 0; k8i < 8; ++k8i) acc += sc[k8i * 32 + t];
          preds[t * 100 + (p - 1)] = acc;
        }
        __syncthreads();
      }
    }

    // ---- gate dot-products
    float a0 = 0.f, a1 = 0.f, a2 = 0.f, a3 = 0.f;
    if (isA) {
      if (p > 0) {
        const float* h = h0_all + (size_t)(p - 1) * 16384;
        int base = tc * 512;
#pragma unroll 4
        for (int kk = 0; kk < 32; ++kk) {
          int k4 = ks * 32 + kk;
          float4 w = *(const float4*)&lds[base + ((k4 ^ tc) << 2)];
          const float* hp = h + k4 * 4;
          float4 h0v = *(const float4*)(hp + (b0 + 0) * 512);
          float4 h1v = *(const float4*)(hp + (b0 + 1) * 512);
          float4 h2v = *(const float4*)(hp + (b0 + 2) * 512);
          float4 h3v = *(const float4*)(hp + (b0 + 3) * 512);
          a0 += w.x * h0v.x + w.y * h0v.y + w.z * h0v.z + w.w * h0v.w;
          a1 += w.x * h1v.x + w.y * h1v.y + w.z * h1v.z + w.w * h1v.w;
          a2 += w.x * h2v.x + w.y * h2v.y + w.z * h2v.z + w.w * h2v.w;
          a3 += w.x * h3v.x + w.y * h3v.y + w.z * h3v.z + w.w * h3v.w;
        }
      }
    } else {
      int half = ks >> 1;
      const float* xv = half ? (p > 0 ? h1_all + (size_t)(p - 1) * 16384 : nullptr)
                             : h0_all + (size_t)p * 16384;
      if (xv) {
        int base = tc * 1024 + half * 512;
#pragma unroll 4
        for (int kk = 0; kk < 64; ++kk) {
          int k4 = (ks & 1) * 64 + kk;
          float4 w = *(const float4*)&lds[base + ((k4 ^ tc) << 2)];
          const float* hp = xv + k4 * 4;
          float4 h0v = *(const float4*)(hp + (b0 + 0) * 512);
          float4 h1v = *(const float4*)(hp + (b0 + 1) * 512);
          float4 h2v = *(const float4*)(hp + (b0 + 2) * 512);
          float4 h3v = *(const float4*)(hp + (b0 + 3) * 512);
          a0 += w.x * h0v.x + w.y * h0v.y + w.z * h0v.z + w.w * h0v.w;
          a1 += w.x * h1v.x + w.y * h1v.y + w.z * h1v.z + w.w * h1v.w;
          a2 += w.x * h2v.x + w.y * h2v.y + w.z * h2v.z + w.w * h2v.w;
          a3 += w.x * h3v.x + w.y * h3v.y + w.z * h3v.z + w.w * h3v.w;
        }
      }
    }

    // ---- reduce 4 k-slices
    float* scratch = lds + 8192;
    if (ks > 0) {
      float* sp = scratch + (t - 64) * 4;
      sp[0] = a0; sp[1] = a1; sp[2] = a2; sp[3] = a3;
    }
    __syncthreads();
    if (t < 64) {
      a0 += scratch[t * 4 + 0] + scratch[(t + 64) * 4 + 0] + scratch[(t + 128) * 4 + 0];
      a1 += scratch[t * 4 + 1] + scratch[(t + 64) * 4 + 1] + scratch[(t + 128) * 4 + 1];
      a2 += scratch[t * 4 + 2] + scratch[(t + 64) * 4 + 2] + scratch[(t + 128) * 4 + 2];
      a3 += scratch[t * 4 + 3] + scratch[(t + 64) * 4 + 3] + scratch[(t + 128) * 4 + 3];
      int grow = (tc >> 1) * 512 + wg * 2 + (tc & 1);
      if (isA) {
        size_t gi = ((size_t)b0 * 100 + (size_t)p) * 2048 + grow;
        a0 += gin[gi];
        a1 += gin[gi + 204800];
        a2 += gin[gi + 409600];
        a3 += gin[gi + 614400];
      } else {
        float bb = b_ih1[grow] + b_hh1[grow];
        a0 += bb; a1 += bb; a2 += bb; a3 += bb;
      }
      float* gbuf = lds + 8960;
      gbuf[tc * 32 + b0 + 0] = a0;
      gbuf[tc * 32 + b0 + 1] = a1;
      gbuf[tc * 32 + b0 + 2] = a2;
      gbuf[tc * 32 + b0 + 3] = a3;
    }
    __syncthreads();
    // ---- cell update (c in registers), write h[p]
    if (t < 64) {
      const float* gbuf = lds + 8960;
      int u = t & 1, b = t >> 1;
      float giv = gbuf[(0 + u) * 32 + b];
      float gfv = gbuf[(2 + u) * 32 + b];
      float ggv = gbuf[(4 + u) * 32 + b];
      float gov = gbuf[(6 + u) * 32 + b];
      float cn = sigf(gfv) * c_reg + sigf(giv) * tanhf(ggv);
      float hn = sigf(gov) * tanhf(cn);
      c_reg = cn;
      float* hdst = (isA ? h0_all : h1_all) + (size_t)p * 16384;
      hdst[b * 512 + wg * 2 + u] = hn;
    }
    __syncthreads();   // drains vmcnt -> h stores complete before flag release
    if (t == 0) st_rel((isA ? flags0 : flags1) + (size_t)p * 256 + wg, 1);
  }

  // ---- final pred[99] by B0
  if (bid == 256) {
    const int* f1 = flags1 + (size_t)99 * 256;
    while (!__syncthreads_and(ld_acq(&f1[t]) != 0)) __builtin_amdgcn_s_sleep(8);
    const float* hp_ = h1_all + (size_t)99 * 16384;
    float* sc = lds + 8192;
    int b = t & 31, k8 = t >> 5;
    const float* hh = hp_ + b * 512 + k8 * 64;
    const float* wp = Wout + k8 * 64;
    float s = 0.f;
#pragma unroll
    for (int i = 0; i < 64; ++i) s += hh[i] * wp[i];
    sc[k8 * 32 + b] = s;
    __syncthreads();
    if (t < 32) {
      float acc = bout[0];
#pragma unroll
      for (int k8i = 0; k8i < 8; ++k8i) acc += sc[k8i * 32 + t];
      preds[t * 100 + 99] = acc;
    }
  }
}

// ---------------- launch ------------------------------------------------------
extern "C" void kernel_launch(void* const* d_in, const int* in_sizes, int n_in,
                              void* d_out, int out_size, void* d_ws, size_t ws_size,
                              hipStream_t stream) {
  (void)in_sizes; (void)n_in; (void)out_size; (void)ws_size;
  const float* x      = (const float*)d_in[0];
  const float* W_img  = (const float*)d_in[1];
  const float* b_img  = (const float*)d_in[2];
  const float* W_obj  = (const float*)d_in[3];
  const float* b_obj  = (const float*)d_in[4];
  const float* W_obj2 = (const float*)d_in[5];
  const float* b_obj2 = (const float*)d_in[6];
  // d_in[7]=W_ah, d_in[8]=W_ac: dead (softmax over size-1 axis == 1)
  const float* W_ih0  = (const float*)d_in[9];
  const float* W_hh0  = (const float*)d_in[10];
  const float* b_ih0  = (const float*)d_in[11];
  const float* b_hh0  = (const float*)d_in[12];
  const float* W_ih1  = (const float*)d_in[13];
  const float* W_hh1  = (const float*)d_in[14];
  const float* b_ih1  = (const float*)d_in[15];
  const float* b_hh1  = (const float*)d_in[16];
  const float* W_out  = (const float*)d_in[17];
  const float* b_out  = (const float*)d_in[18];

  float* out    = (float*)d_out;
  float* alphas = out;            // 60800
  float* preds  = out + 60800;    // 3200

  float* ws     = (float*)d_ws;
  float* z      = ws;                     // 13107200
  float* zW     = z + 13107200;           // 1638400
  float* xl     = zW + 1638400;           // 3276800
  float* gin    = xl + 3276800;           // 6553600
  float* s1     = gin + 6553600;          // 3200
  float* s2     = s1 + 3200;              // 3200
  float* vb     = s2 + 3200;              // 512
  float* h0_all = vb + 512;               // 1638400  (100 x 32 x 512)
  float* h1_all = h0_all + 1638400;       // 1638400
  int*   flags0 = (int*)(h1_all + 1638400);   // 25600 ints
  int*   flags1 = flags0 + 25600;             // 25600 ints

  // flags must be zero at the start of every call (incl. graph replays)
  hipMemsetAsync(flags0, 0, 2 * 25600 * sizeof(int), stream);

  mask_z_kernel<<<3200, 256, 0, stream>>>(x, z, s1, s2, alphas);
  colvec_kernel<<<2, 256, 0, stream>>>(W_obj2, b_obj, vb);
  // img_feat = x[:,:,0,:] @ W_img^T + b_img  -> xl[:, 0:512]
  gemm_atb<<<dim3(50, 8), 256, 0, stream>>>(x, 81920, W_img, 4096, xl, 1024,
      b_img, nullptr, nullptr, nullptr, nullptr, nullptr);
  // zW = z @ W_obj^T
  gemm_atb<<<dim3(50, 8), 256, 0, stream>>>(z, 4096, W_obj, 4096, zW, 512,
      nullptr, nullptr, nullptr, nullptr, nullptr, nullptr);
  // w_obj = zW @ W_obj2^T + s2*vb + s1*b_obj2 -> xl[:, 512:1024]
  gemm_atb<<<dim3(50, 8), 256, 0, stream>>>(zW, 512, W_obj2, 512, xl + 512, 1024,
      nullptr, nullptr, s2, vb, s1, b_obj2);
  // gin = xl @ W_ih0^T + b_ih0 + b_hh0
  gemm_atb<<<dim3(50, 32), 256, 0, stream>>>(xl, 1024, W_ih0, 1024, gin, 2048,
      b_ih0, b_hh0, nullptr, nullptr, nullptr, nullptr);

  // whole recurrence in ONE persistent kernel
  lstm_persist<<<512, 256, 0, stream>>>(gin, W_hh0, W_ih1, W_hh1, b_ih1, b_hh1,
      W_out, b_out, h0_all, h1_all, flags0, flags1, preds);
}

// Round 5
// 6140.730 us; speedup vs baseline: 1.4072x; 1.4072x over previous
//
#include <hip/hip_runtime.h>

// B=32, N=100, K=20, D=4096, DI=DO=H=512, 4H=2048, M=B*N=3200
// ws: z 13107200 | zW 1638400 | xl 3276800 | gin 6553600 | s1 3200 | s2 3200
//     vb 512 | h0_all 1638400 | h1_all 1638400 | flags 2*12800 ints
// Wpk0 (1048576) and Wpk1 (2097152) live INSIDE z (packed after the zW GEMM,
// when z is dead). Recurrence: 256 persistent blocks (128 L0 + 128 L1), each
// owns 4 units; thread = (gate-row, batch) computes a full dot product ->
// h read exactly once per block (same-address lanes merge in the coalescer);
// weights stream K-major from local L2.

#define NSTEP 100

__device__ __forceinline__ float sigf(float x) { return 1.0f / (1.0f + __expf(-x)); }
__device__ __forceinline__ int ld_acq(const int* p) {
  return __hip_atomic_load(p, __ATOMIC_ACQUIRE, __HIP_MEMORY_SCOPE_AGENT);
}
__device__ __forceinline__ void st_rel(int* p, int v) {
  __hip_atomic_store(p, v, __ATOMIC_RELEASE, __HIP_MEMORY_SCOPE_AGENT);
}

// ---------------- Kernel 1: obj_mask (-> alphas), z = sum_k m_k^2 x_k, s1, s2 ----
__global__ __launch_bounds__(256) void mask_z_kernel(
    const float* __restrict__ x, float* __restrict__ z,
    float* __restrict__ s1, float* __restrict__ s2, float* __restrict__ alphas)
{
  int m = blockIdx.x;            // 0..3199
  int b = m / 100, n = m % 100;
  int t = threadIdx.x;           // 256
  const float* xb = x + (size_t)m * 81920;   // x[b,n,0,0]
  __shared__ float red[4];
  float zv[16];
#pragma unroll
  for (int i = 0; i < 16; ++i) zv[i] = 0.f;
  float s1v = 0.f, s2v = 0.f;
  for (int k = 1; k < 20; ++k) {
    const float4* row = (const float4*)(xb + (size_t)k * 4096);
    float4 v0 = row[t], v1 = row[t + 256], v2 = row[t + 512], v3 = row[t + 768];
    float ps = v0.x + v0.y + v0.z + v0.w + v1.x + v1.y + v1.z + v1.w
             + v2.x + v2.y + v2.z + v2.w + v3.x + v3.y + v3.z + v3.w;
#pragma unroll
    for (int off = 32; off >= 1; off >>= 1) ps += __shfl_down(ps, off);
    if ((t & 63) == 0) red[t >> 6] = ps;
    __syncthreads();
    float mk = red[0] + red[1] + red[2] + red[3];
    __syncthreads();
    float mk2 = mk * mk;
    s1v += mk; s2v += mk2;
    if (t == 0) alphas[((size_t)n * 32 + (size_t)b) * 19 + (k - 1)] = mk;
    zv[0] += mk2 * v0.x; zv[1] += mk2 * v0.y; zv[2] += mk2 * v0.z; zv[3] += mk2 * v0.w;
    zv[4] += mk2 * v1.x; zv[5] += mk2 * v1.y; zv[6] += mk2 * v1.z; zv[7] += mk2 * v1.w;
    zv[8] += mk2 * v2.x; zv[9] += mk2 * v2.y; zv[10] += mk2 * v2.z; zv[11] += mk2 * v2.w;
    zv[12] += mk2 * v3.x; zv[13] += mk2 * v3.y; zv[14] += mk2 * v3.z; zv[15] += mk2 * v3.w;
  }
  float4* zr = (float4*)(z + (size_t)m * 4096);
  zr[t]       = make_float4(zv[0], zv[1], zv[2], zv[3]);
  zr[t + 256] = make_float4(zv[4], zv[5], zv[6], zv[7]);
  zr[t + 512] = make_float4(zv[8], zv[9], zv[10], zv[11]);
  zr[t + 768] = make_float4(zv[12], zv[13], zv[14], zv[15]);
  if (t == 0) { s1[m] = s1v; s2[m] = s2v; }
}

// ---------------- tiny: vb[j] = sum_i W_obj2[j,i] * b_obj[i] --------------------
__global__ void colvec_kernel(const float* __restrict__ W2,
                              const float* __restrict__ bo, float* __restrict__ vb)
{
  int j = blockIdx.x * 256 + threadIdx.x;
  if (j < 512) {
    float s = 0.f;
    for (int i = 0; i < 512; ++i) s += W2[(size_t)j * 512 + i] * bo[i];
    vb[j] = s;
  }
}

// ---------------- fp32 GEMM (R2 version) ---------------------------------------
__global__ __launch_bounds__(256) void gemm_atb(
    const float* __restrict__ A, int lda,
    const float* __restrict__ W, int K,
    float* __restrict__ C, int ldc,
    const float* __restrict__ bias1, const float* __restrict__ bias2,
    const float* __restrict__ rs1, const float* __restrict__ cv1,
    const float* __restrict__ rs2, const float* __restrict__ cv2)
{
  __shared__ __align__(16) float As[32 * 76];
  __shared__ __align__(16) float Ws[32 * 76];
  int t = threadIdx.x;
  int m0 = blockIdx.x * 64, n0 = blockIdx.y * 64;
  int sr = t >> 3;
  int sc = t & 7;
  int r0 = (t >> 4) * 4, c0 = (t & 15) * 4;

  float acc[4][4];
#pragma unroll
  for (int i = 0; i < 4; ++i)
#pragma unroll
    for (int j = 0; j < 4; ++j) acc[i][j] = 0.f;

  const float* Ap0 = A + (size_t)(m0 + sr) * lda + sc * 4;
  const float* Ap1 = A + (size_t)(m0 + sr + 32) * lda + sc * 4;
  const float* Wp0 = W + (size_t)(n0 + sr) * K + sc * 4;
  const float* Wp1 = W + (size_t)(n0 + sr + 32) * K + sc * 4;

  float4 a0 = *(const float4*)(Ap0);
  float4 a1 = *(const float4*)(Ap1);
  float4 w0 = *(const float4*)(Wp0);
  float4 w1 = *(const float4*)(Wp1);

  for (int k0 = 0; k0 < K; k0 += 32) {
    int kb = sc * 4;
#pragma unroll
    for (int j = 0; j < 4; ++j) {
      float aj0 = (j == 0) ? a0.x : (j == 1) ? a0.y : (j == 2) ? a0.z : a0.w;
      float aj1 = (j == 0) ? a1.x : (j == 1) ? a1.y : (j == 2) ? a1.z : a1.w;
      float wj0 = (j == 0) ? w0.x : (j == 1) ? w0.y : (j == 2) ? w0.z : w0.w;
      float wj1 = (j == 0) ? w1.x : (j == 1) ? w1.y : (j == 2) ? w1.z : w1.w;
      As[(kb + j) * 76 + sr]      = aj0;
      As[(kb + j) * 76 + sr + 32] = aj1;
      Ws[(kb + j) * 76 + sr]      = wj0;
      Ws[(kb + j) * 76 + sr + 32] = wj1;
    }
    __syncthreads();
    if (k0 + 32 < K) {
      a0 = *(const float4*)(Ap0 + k0 + 32);
      a1 = *(const float4*)(Ap1 + k0 + 32);
      w0 = *(const float4*)(Wp0 + k0 + 32);
      w1 = *(const float4*)(Wp1 + k0 + 32);
    }
#pragma unroll 8
    for (int kk = 0; kk < 32; ++kk) {
      float4 av = *(const float4*)&As[kk * 76 + r0];
      float4 wv = *(const float4*)&Ws[kk * 76 + c0];
      float ar[4] = {av.x, av.y, av.z, av.w};
      float wr[4] = {wv.x, wv.y, wv.z, wv.w};
#pragma unroll
      for (int i = 0; i < 4; ++i)
#pragma unroll
        for (int j = 0; j < 4; ++j) acc[i][j] += ar[i] * wr[j];
    }
    __syncthreads();
  }
#pragma unroll
  for (int i = 0; i < 4; ++i) {
    int m = m0 + r0 + i;
    float r1v = rs1 ? rs1[m] : 0.f;
    float r2v = rs2 ? rs2[m] : 0.f;
#pragma unroll
    for (int j = 0; j < 4; ++j) {
      int n = n0 + c0 + j;
      float v = acc[i][j];
      if (bias1) v += bias1[n];
      if (bias2) v += bias2[n];
      if (cv1) v += r1v * cv1[n];
      if (cv2) v += r2v * cv2[n];
      C[(size_t)m * ldc + n] = v;
    }
  }
}

// ---------------- one-time K-major weight pack ----------------------------------
// Wpk0[((j*128+kg)*16+r)*4+c] = W_hh0[grow, kg*4+c],  grow=(r>>2)*512 + j*4 + (r&3)
// Wpk1[((j*256+kg)*16+r)*4+c] = kg<128 ? W_ih1[grow, kg*4+c] : W_hh1[grow,(kg-128)*4+c]
__global__ __launch_bounds__(256) void pack_w(
    const float* __restrict__ Whh0, const float* __restrict__ Wih1,
    const float* __restrict__ Whh1, float* __restrict__ Wpk0, float* __restrict__ Wpk1)
{
  int id = blockIdx.x * 256 + threadIdx.x;     // 0..786431
  if (id < 262144) {
    int j = id / 2048, rem = id % 2048, kg = rem / 16, r = rem % 16;
    int grow = (r >> 2) * 512 + j * 4 + (r & 3);
    float4 v = *(const float4*)(Whh0 + (size_t)grow * 512 + kg * 4);
    *(float4*)(Wpk0 + (size_t)id * 4) = v;
  } else {
    int id2 = id - 262144;
    int j = id2 / 4096, rem = id2 % 4096, kg = rem / 16, r = rem % 16;
    int grow = (r >> 2) * 512 + j * 4 + (r & 3);
    const float* src = (kg < 128) ? (Wih1 + (size_t)grow * 512 + kg * 4)
                                  : (Whh1 + (size_t)grow * 512 + (kg - 128) * 4);
    float4 v = *(const float4*)(src);
    *(float4*)(Wpk1 + (size_t)id2 * 4) = v;
  }
}

// ---------------- Persistent LSTM recurrence -----------------------------------
// 256 blocks x 512 threads. bid<128: layer0 block j=bid (units j*4..j*4+3);
// bid>=128: layer1 block j=bid-128. Thread (r=t&15, bg=t>>4): one gate-row,
// one batch, full-K dot product (no cross-thread reduction). Per-producer
// flags: 128 per step per layer, release after h stores drain.
__global__ __launch_bounds__(512) void lstm_persist(
    const float* __restrict__ gin,
    const float* __restrict__ Wpk0, const float* __restrict__ Wpk1,
    const float* __restrict__ b_ih1, const float* __restrict__ b_hh1,
    const float* __restrict__ Wout, const float* __restrict__ bout,
    float* __restrict__ h0_all, float* __restrict__ h1_all,
    int* __restrict__ flags0, int* __restrict__ flags1,
    float* __restrict__ preds)
{
  __shared__ float gbuf[16 * 33];
  __shared__ float psum[32 * 17];
  int bid = blockIdx.x, t = threadIdx.x;
  bool isA = bid < 128;
  int j = isA ? bid : bid - 128;
  int r = t & 15, bg = t >> 4;                 // gate-row 0..15, batch 0..31
  int grow = (r >> 2) * 512 + j * 4 + (r & 3); // global gate row
  float c_reg = 0.f;                           // t<128: u=t>>5, b=t&31

  for (int p = 0; p < NSTEP; ++p) {
    // ---- dependency wait -------------------------------------------------
    if (isA) {
      if (p > 0) {
        const int* f = flags0 + (p - 1) * 128;
        for (;;) {
          bool ok = (t >= 128) || (ld_acq(&f[t]) != 0);
          if (__syncthreads_and(ok)) break;
          __builtin_amdgcn_s_sleep(2);
        }
      }
    } else {
      const int* f0 = flags0 + p * 128;
      const int* f1 = flags1 + (p - 1) * 128;
      for (;;) {
        bool ok = (t >= 128) ||
                  ((ld_acq(&f0[t]) != 0) && (p == 0 || ld_acq(&f1[t]) != 0));
        if (__syncthreads_and(ok)) break;
        __builtin_amdgcn_s_sleep(2);
      }
      if (bid == 128 && p > 0) {   // pred[p-1] from h1[p-1] (just acquired)
        const float* h1p = h1_all + (size_t)(p - 1) * 16384;
        int b = t >> 4, ks = t & 15;
        const float* hh = h1p + b * 512 + ks * 32;
        const float* wp = Wout + ks * 32;
        float s = 0.f;
#pragma unroll
        for (int i = 0; i < 32; ++i) s += hh[i] * wp[i];
        psum[b * 17 + ks] = s;
        __syncthreads();
        if (t < 32) {
          float acc2 = bout[0];
#pragma unroll
          for (int k2 = 0; k2 < 16; ++k2) acc2 += psum[t * 17 + k2];
          preds[t * 100 + (p - 1)] = acc2;
        }
        __syncthreads();
      }
    }

    // ---- full-K gate dot product ----------------------------------------
    float acc = 0.f;
    if (isA) {
      if (p > 0) {
        const float* h  = h0_all + (size_t)(p - 1) * 16384 + bg * 512;
        const float* Wp = Wpk0 + (size_t)j * 8192 + r * 4;
#pragma unroll 8
        for (int kg = 0; kg < 128; ++kg) {
          float4 w  = *(const float4*)(Wp + kg * 64);
          float4 hv = *(const float4*)(h + kg * 4);
          acc += w.x * hv.x + w.y * hv.y + w.z * hv.z + w.w * hv.w;
        }
      }
      acc += gin[((size_t)bg * 100 + p) * 2048 + grow];
    } else {
      acc = b_ih1[grow] + b_hh1[grow];
      const float* Wp  = Wpk1 + (size_t)j * 16384 + r * 4;
      const float* h0p = h0_all + (size_t)p * 16384 + bg * 512;
#pragma unroll 8
      for (int kg = 0; kg < 128; ++kg) {
        float4 w  = *(const float4*)(Wp + kg * 64);
        float4 hv = *(const float4*)(h0p + kg * 4);
        acc += w.x * hv.x + w.y * hv.y + w.z * hv.z + w.w * hv.w;
      }
      if (p > 0) {
        const float* h1p = h1_all + (size_t)(p - 1) * 16384 + bg * 512;
#pragma unroll 8
        for (int kg = 0; kg < 128; ++kg) {
          float4 w  = *(const float4*)(Wp + 8192 + kg * 64);
          float4 hv = *(const float4*)(h1p + kg * 4);
          acc += w.x * hv.x + w.y * hv.y + w.z * hv.z + w.w * hv.w;
        }
      }
    }
    gbuf[r * 33 + bg] = acc;
    __syncthreads();

    // ---- cell update: thread t<128 owns (u=t>>5, b=t&31) -----------------
    if (t < 128) {
      int u = t >> 5, b = t & 31;
      float giv = gbuf[(0 + u) * 33 + b];
      float gfv = gbuf[(4 + u) * 33 + b];
      float ggv = gbuf[(8 + u) * 33 + b];
      float gov = gbuf[(12 + u) * 33 + b];
      float cn = sigf(gfv) * c_reg + sigf(giv) * tanhf(ggv);
      float hn = sigf(gov) * tanhf(cn);
      c_reg = cn;
      float* hd = (isA ? h0_all : h1_all) + (size_t)p * 16384;
      hd[b * 512 + j * 4 + u] = hn;
    }
    __syncthreads();   // drains h stores (vmcnt) before release
    if (t == 0) st_rel((isA ? flags0 : flags1) + p * 128 + j, 1);
  }

  // ---- final pred[99] ----------------------------------------------------
  if (bid == 128) {
    const int* f1 = flags1 + 99 * 128;
    for (;;) {
      bool ok = (t >= 128) || (ld_acq(&f1[t]) != 0);
      if (__syncthreads_and(ok)) break;
      __builtin_amdgcn_s_sleep(2);
    }
    const float* h1p = h1_all + (size_t)99 * 16384;
    int b = t >> 4, ks = t & 15;
    const float* hh = h1p + b * 512 + ks * 32;
    const float* wp = Wout + ks * 32;
    float s = 0.f;
#pragma unroll
    for (int i = 0; i < 32; ++i) s += hh[i] * wp[i];
    psum[b * 17 + ks] = s;
    __syncthreads();
    if (t < 32) {
      float acc2 = bout[0];
#pragma unroll
      for (int k2 = 0; k2 < 16; ++k2) acc2 += psum[t * 17 + k2];
      preds[t * 100 + 99] = acc2;
    }
  }
}

// ---------------- launch ------------------------------------------------------
extern "C" void kernel_launch(void* const* d_in, const int* in_sizes, int n_in,
                              void* d_out, int out_size, void* d_ws, size_t ws_size,
                              hipStream_t stream) {
  (void)in_sizes; (void)n_in; (void)out_size; (void)ws_size;
  const float* x      = (const float*)d_in[0];
  const float* W_img  = (const float*)d_in[1];
  const float* b_img  = (const float*)d_in[2];
  const float* W_obj  = (const float*)d_in[3];
  const float* b_obj  = (const float*)d_in[4];
  const float* W_obj2 = (const float*)d_in[5];
  const float* b_obj2 = (const float*)d_in[6];
  // d_in[7]=W_ah, d_in[8]=W_ac: dead (softmax over size-1 axis == 1)
  const float* W_ih0  = (const float*)d_in[9];
  const float* W_hh0  = (const float*)d_in[10];
  const float* b_ih0  = (const float*)d_in[11];
  const float* b_hh0  = (const float*)d_in[12];
  const float* W_ih1  = (const float*)d_in[13];
  const float* W_hh1  = (const float*)d_in[14];
  const float* b_ih1  = (const float*)d_in[15];
  const float* b_hh1  = (const float*)d_in[16];
  const float* W_out  = (const float*)d_in[17];
  const float* b_out  = (const float*)d_in[18];

  float* out    = (float*)d_out;
  float* alphas = out;            // 60800
  float* preds  = out + 60800;    // 3200

  float* ws     = (float*)d_ws;
  float* z      = ws;                     // 13107200 (dead after zW GEMM)
  float* Wpk0   = z;                      // 1048576  (packed after zW GEMM)
  float* Wpk1   = z + 1048576;            // 2097152
  float* zW     = z + 13107200;           // 1638400
  float* xl     = zW + 1638400;           // 3276800
  float* gin    = xl + 3276800;           // 6553600
  float* s1     = gin + 6553600;          // 3200
  float* s2     = s1 + 3200;              // 3200
  float* vb     = s2 + 3200;              // 512
  float* h0_all = vb + 512;               // 1638400  (100 x 32 x 512)
  float* h1_all = h0_all + 1638400;       // 1638400
  int*   flags0 = (int*)(h1_all + 1638400);   // 12800 ints
  int*   flags1 = flags0 + 12800;             // 12800 ints

  // flags must be zero at the start of every call (incl. graph replays)
  hipMemsetAsync(flags0, 0, 2 * 12800 * sizeof(int), stream);

  mask_z_kernel<<<3200, 256, 0, stream>>>(x, z, s1, s2, alphas);
  colvec_kernel<<<2, 256, 0, stream>>>(W_obj2, b_obj, vb);
  // img_feat = x[:,:,0,:] @ W_img^T + b_img  -> xl[:, 0:512]
  gemm_atb<<<dim3(50, 8), 256, 0, stream>>>(x, 81920, W_img, 4096, xl, 1024,
      b_img, nullptr, nullptr, nullptr, nullptr, nullptr);
  // zW = z @ W_obj^T
  gemm_atb<<<dim3(50, 8), 256, 0, stream>>>(z, 4096, W_obj, 4096, zW, 512,
      nullptr, nullptr, nullptr, nullptr, nullptr, nullptr);
  // z is now dead: pack weights K-major into it
  pack_w<<<3072, 256, 0, stream>>>(W_hh0, W_ih1, W_hh1, Wpk0, Wpk1);
  // w_obj = zW @ W_obj2^T + s2*vb + s1*b_obj2 -> xl[:, 512:1024]
  gemm_atb<<<dim3(50, 8), 256, 0, stream>>>(zW, 512, W_obj2, 512, xl + 512, 1024,
      nullptr, nullptr, s2, vb, s1, b_obj2);
  // gin = xl @ W_ih0^T + b_ih0 + b_hh0
  gemm_atb<<<dim3(50, 32), 256, 0, stream>>>(xl, 1024, W_ih0, 1024, gin, 2048,
      b_ih0, b_hh0, nullptr, nullptr, nullptr, nullptr);

  // whole recurrence in ONE persistent kernel (256 blocks: 128 L0 + 128 L1)
  lstm_persist<<<256, 512, 0, stream>>>(gin, Wpk0, Wpk1, b_ih1, b_hh1,
      W_out, b_out, h0_all, h1_all, flags0, flags1, preds);
}

// Round 6
// 4914.100 us; speedup vs baseline: 1.7584x; 1.2496x over previous
//
#include <hip/hip_runtime.h>

// B=32, N=100, K=20, D=4096, DI=DO=H=512, 4H=2048, M=B*N=3200
// Pipeline: mask_z -> GEMMs (img, zW, w_obj, gin) -> 102 lean phase launches.
// Phase p: L0 computes h0[p] (128 blocks); L1 computes h1[p-1] (128 blocks);
// block 128 also emits pred[p-2]. Kernel boundaries provide coherence (no atomics).

#define NSTEP 100

__device__ __forceinline__ float sigf(float x) { return 1.0f / (1.0f + __expf(-x)); }

// ---------------- Kernel 1: obj_mask (-> alphas), z = sum_k m_k^2 x_k, s1, s2 ----
__global__ __launch_bounds__(256) void mask_z_kernel(
    const float* __restrict__ x, float* __restrict__ z,
    float* __restrict__ s1, float* __restrict__ s2, float* __restrict__ alphas)
{
  int m = blockIdx.x;            // 0..3199
  int b = m / 100, n = m % 100;
  int t = threadIdx.x;           // 256
  const float* xb = x + (size_t)m * 81920;   // x[b,n,0,0]
  __shared__ float red[4];
  float zv[16];
#pragma unroll
  for (int i = 0; i < 16; ++i) zv[i] = 0.f;
  float s1v = 0.f, s2v = 0.f;
  for (int k = 1; k < 20; ++k) {
    const float4* row = (const float4*)(xb + (size_t)k * 4096);
    float4 v0 = row[t], v1 = row[t + 256], v2 = row[t + 512], v3 = row[t + 768];
    float ps = v0.x + v0.y + v0.z + v0.w + v1.x + v1.y + v1.z + v1.w
             + v2.x + v2.y + v2.z + v2.w + v3.x + v3.y + v3.z + v3.w;
#pragma unroll
    for (int off = 32; off >= 1; off >>= 1) ps += __shfl_down(ps, off);
    if ((t & 63) == 0) red[t >> 6] = ps;
    __syncthreads();
    float mk = red[0] + red[1] + red[2] + red[3];
    __syncthreads();
    float mk2 = mk * mk;
    s1v += mk; s2v += mk2;
    if (t == 0) alphas[((size_t)n * 32 + (size_t)b) * 19 + (k - 1)] = mk;
    zv[0] += mk2 * v0.x; zv[1] += mk2 * v0.y; zv[2] += mk2 * v0.z; zv[3] += mk2 * v0.w;
    zv[4] += mk2 * v1.x; zv[5] += mk2 * v1.y; zv[6] += mk2 * v1.z; zv[7] += mk2 * v1.w;
    zv[8] += mk2 * v2.x; zv[9] += mk2 * v2.y; zv[10] += mk2 * v2.z; zv[11] += mk2 * v2.w;
    zv[12] += mk2 * v3.x; zv[13] += mk2 * v3.y; zv[14] += mk2 * v3.z; zv[15] += mk2 * v3.w;
  }
  float4* zr = (float4*)(z + (size_t)m * 4096);
  zr[t]       = make_float4(zv[0], zv[1], zv[2], zv[3]);
  zr[t + 256] = make_float4(zv[4], zv[5], zv[6], zv[7]);
  zr[t + 512] = make_float4(zv[8], zv[9], zv[10], zv[11]);
  zr[t + 768] = make_float4(zv[12], zv[13], zv[14], zv[15]);
  if (t == 0) { s1[m] = s1v; s2[m] = s2v; }
}

// ---------------- tiny: vb[j] = sum_i W_obj2[j,i] * b_obj[i] --------------------
__global__ void colvec_kernel(const float* __restrict__ W2,
                              const float* __restrict__ bo, float* __restrict__ vb)
{
  int j = blockIdx.x * 256 + threadIdx.x;
  if (j < 512) {
    float s = 0.f;
    for (int i = 0; i < 512; ++i) s += W2[(size_t)j * 512 + i] * bo[i];
    vb[j] = s;
  }
}

// ---------------- fp32 GEMM (R2 version) ---------------------------------------
__global__ __launch_bounds__(256) void gemm_atb(
    const float* __restrict__ A, int lda,
    const float* __restrict__ W, int K,
    float* __restrict__ C, int ldc,
    const float* __restrict__ bias1, const float* __restrict__ bias2,
    const float* __restrict__ rs1, const float* __restrict__ cv1,
    const float* __restrict__ rs2, const float* __restrict__ cv2)
{
  __shared__ __align__(16) float As[32 * 76];
  __shared__ __align__(16) float Ws[32 * 76];
  int t = threadIdx.x;
  int m0 = blockIdx.x * 64, n0 = blockIdx.y * 64;
  int sr = t >> 3;
  int sc = t & 7;
  int r0 = (t >> 4) * 4, c0 = (t & 15) * 4;

  float acc[4][4];
#pragma unroll
  for (int i = 0; i < 4; ++i)
#pragma unroll
    for (int j = 0; j < 4; ++j) acc[i][j] = 0.f;

  const float* Ap0 = A + (size_t)(m0 + sr) * lda + sc * 4;
  const float* Ap1 = A + (size_t)(m0 + sr + 32) * lda + sc * 4;
  const float* Wp0 = W + (size_t)(n0 + sr) * K + sc * 4;
  const float* Wp1 = W + (size_t)(n0 + sr + 32) * K + sc * 4;

  float4 a0 = *(const float4*)(Ap0);
  float4 a1 = *(const float4*)(Ap1);
  float4 w0 = *(const float4*)(Wp0);
  float4 w1 = *(const float4*)(Wp1);

  for (int k0 = 0; k0 < K; k0 += 32) {
    int kb = sc * 4;
#pragma unroll
    for (int j = 0; j < 4; ++j) {
      float aj0 = (j == 0) ? a0.x : (j == 1) ? a0.y : (j == 2) ? a0.z : a0.w;
      float aj1 = (j == 0) ? a1.x : (j == 1) ? a1.y : (j == 2) ? a1.z : a1.w;
      float wj0 = (j == 0) ? w0.x : (j == 1) ? w0.y : (j == 2) ? w0.z : w0.w;
      float wj1 = (j == 0) ? w1.x : (j == 1) ? w1.y : (j == 2) ? w1.z : w1.w;
      As[(kb + j) * 76 + sr]      = aj0;
      As[(kb + j) * 76 + sr + 32] = aj1;
      Ws[(kb + j) * 76 + sr]      = wj0;
      Ws[(kb + j) * 76 + sr + 32] = wj1;
    }
    __syncthreads();
    if (k0 + 32 < K) {
      a0 = *(const float4*)(Ap0 + k0 + 32);
      a1 = *(const float4*)(Ap1 + k0 + 32);
      w0 = *(const float4*)(Wp0 + k0 + 32);
      w1 = *(const float4*)(Wp1 + k0 + 32);
    }
#pragma unroll 8
    for (int kk = 0; kk < 32; ++kk) {
      float4 av = *(const float4*)&As[kk * 76 + r0];
      float4 wv = *(const float4*)&Ws[kk * 76 + c0];
      float ar[4] = {av.x, av.y, av.z, av.w};
      float wr[4] = {wv.x, wv.y, wv.z, wv.w};
#pragma unroll
      for (int i = 0; i < 4; ++i)
#pragma unroll
        for (int j = 0; j < 4; ++j) acc[i][j] += ar[i] * wr[j];
    }
    __syncthreads();
  }
#pragma unroll
  for (int i = 0; i < 4; ++i) {
    int m = m0 + r0 + i;
    float r1v = rs1 ? rs1[m] : 0.f;
    float r2v = rs2 ? rs2[m] : 0.f;
#pragma unroll
    for (int j = 0; j < 4; ++j) {
      int n = n0 + c0 + j;
      float v = acc[i][j];
      if (bias1) v += bias1[n];
      if (bias2) v += bias2[n];
      if (cv1) v += r1v * cv1[n];
      if (cv2) v += r2v * cv2[n];
      C[(size_t)m * ldc + n] = v;
    }
  }
}

// ---------------- one-time K-major weight pack ----------------------------------
// Wpk0[j*8192 + kg*64 + r*4 + c] = W_hh0[grow, kg*4+c], grow=(r>>2)*512 + j*4 + (r&3)
// Wpk1[j*16384 + kg*64 + r*4 + c] (kg<128: W_ih1; kg>=128: W_hh1[.., (kg-128)*4+c])
__global__ __launch_bounds__(256) void pack_w(
    const float* __restrict__ Whh0, const float* __restrict__ Wih1,
    const float* __restrict__ Whh1, float* __restrict__ Wpk0, float* __restrict__ Wpk1)
{
  int id = blockIdx.x * 256 + threadIdx.x;     // 0..786431
  if (id < 262144) {
    int j = id / 2048, rem = id % 2048, kg = rem / 16, r = rem % 16;
    int grow = (r >> 2) * 512 + j * 4 + (r & 3);
    float4 v = *(const float4*)(Whh0 + (size_t)grow * 512 + kg * 4);
    *(float4*)(Wpk0 + (size_t)id * 4) = v;
  } else {
    int id2 = id - 262144;
    int j = id2 / 4096, rem = id2 % 4096, kg = rem / 16, r = rem % 16;
    int grow = (r >> 2) * 512 + j * 4 + (r & 3);
    const float* src = (kg < 128) ? (Wih1 + (size_t)grow * 512 + kg * 4)
                                  : (Whh1 + (size_t)grow * 512 + (kg - 128) * 4);
    float4 v = *(const float4*)(src);
    *(float4*)(Wpk1 + (size_t)id2 * 4) = v;
  }
}

// ---------------- Lean per-phase LSTM kernel ------------------------------------
// 256 blocks x 512 threads. bid<128: L0 block j (units j*4..+3), step p.
// bid>=128: L1 block j=bid-128, step q=p-1. Thread (r=t&15, bg=t>>4): one
// gate-row, one batch, full-K dot (no redundancy). Coherence via launch bounds.
__global__ __launch_bounds__(512) void lstm_phase2(
    const float* __restrict__ gin,
    const float* __restrict__ Wpk0, const float* __restrict__ Wpk1,
    const float* __restrict__ b_ih1, const float* __restrict__ b_hh1,
    const float* __restrict__ Wout, const float* __restrict__ bout,
    float* __restrict__ h0_all, float* __restrict__ h1_all,
    float* __restrict__ c0_st, float* __restrict__ c1_st,
    float* __restrict__ preds, int p)
{
  __shared__ float gbuf[16 * 33];
  __shared__ float psum[32 * 17];
  int bid = blockIdx.x, t = threadIdx.x;
  bool isA = bid < 128;
  int j = isA ? bid : bid - 128;
  int q = p - 1;                               // L1's step
  int r = t & 15, bg = t >> 4;                 // gate-row 0..15, batch 0..31
  int grow = (r >> 2) * 512 + j * 4 + (r & 3); // global gate row
  bool activeA = isA && (p <= 99);
  bool activeB = !isA && (q >= 0) && (q <= 99);

  float acc = 0.f;
  if (activeA) {
    acc = gin[((size_t)bg * 100 + p) * 2048 + grow];
    if (p > 0) {
      const float* h  = h0_all + (size_t)(p - 1) * 16384 + bg * 512;
      const float* Wp = Wpk0 + (size_t)j * 8192 + r * 4;
#pragma unroll 8
      for (int kg = 0; kg < 128; ++kg) {
        float4 w  = *(const float4*)(Wp + kg * 64);
        float4 hv = *(const float4*)(h + kg * 4);
        acc += w.x * hv.x + w.y * hv.y + w.z * hv.z + w.w * hv.w;
      }
    }
  } else if (activeB) {
    acc = b_ih1[grow] + b_hh1[grow];
    const float* Wp  = Wpk1 + (size_t)j * 16384 + r * 4;
    const float* h0p = h0_all + (size_t)q * 16384 + bg * 512;
#pragma unroll 8
    for (int kg = 0; kg < 128; ++kg) {
      float4 w  = *(const float4*)(Wp + kg * 64);
      float4 hv = *(const float4*)(h0p + kg * 4);
      acc += w.x * hv.x + w.y * hv.y + w.z * hv.z + w.w * hv.w;
    }
    if (q > 0) {
      const float* h1p = h1_all + (size_t)(q - 1) * 16384 + bg * 512;
#pragma unroll 8
      for (int kg = 0; kg < 128; ++kg) {
        float4 w  = *(const float4*)(Wp + 8192 + kg * 64);
        float4 hv = *(const float4*)(h1p + kg * 4);
        acc += w.x * hv.x + w.y * hv.y + w.z * hv.z + w.w * hv.w;
      }
    }
  }
  gbuf[r * 33 + bg] = acc;
  __syncthreads();

  // ---- cell update: thread t<128 owns (u=t>>5, b=t&31)
  if ((activeA || activeB) && t < 128) {
    int u = t >> 5, b = t & 31;
    float giv = gbuf[(0 + u) * 33 + b];
    float gfv = gbuf[(4 + u) * 33 + b];
    float ggv = gbuf[(8 + u) * 33 + b];
    float gov = gbuf[(12 + u) * 33 + b];
    int ci = b * 512 + j * 4 + u;
    float* cs = isA ? c0_st : c1_st;
    float cp = cs[ci];
    float cn = sigf(gfv) * cp + sigf(giv) * tanhf(ggv);
    float hn = sigf(gov) * tanhf(cn);
    cs[ci] = cn;
    int step = isA ? p : q;
    float* hd = (isA ? h0_all : h1_all) + (size_t)step * 16384;
    hd[ci] = hn;
  }

  // ---- pred[p-2] from h1[p-2], block 128 only (block-uniform branch)
  if (bid == 128 && p >= 2) {
    const float* h1p = h1_all + (size_t)(p - 2) * 16384;
    int b = t >> 4, ks = t & 15;
    const float* hh = h1p + b * 512 + ks * 32;
    const float* wp = Wout + ks * 32;
    float s = 0.f;
#pragma unroll
    for (int i = 0; i < 32; ++i) s += hh[i] * wp[i];
    psum[b * 17 + ks] = s;
    __syncthreads();
    if (t < 32) {
      float acc2 = bout[0];
#pragma unroll
      for (int k2 = 0; k2 < 16; ++k2) acc2 += psum[t * 17 + k2];
      preds[t * 100 + (p - 2)] = acc2;
    }
  }
}

// ---------------- launch ------------------------------------------------------
extern "C" void kernel_launch(void* const* d_in, const int* in_sizes, int n_in,
                              void* d_out, int out_size, void* d_ws, size_t ws_size,
                              hipStream_t stream) {
  (void)in_sizes; (void)n_in; (void)out_size; (void)ws_size;
  const float* x      = (const float*)d_in[0];
  const float* W_img  = (const float*)d_in[1];
  const float* b_img  = (const float*)d_in[2];
  const float* W_obj  = (const float*)d_in[3];
  const float* b_obj  = (const float*)d_in[4];
  const float* W_obj2 = (const float*)d_in[5];
  const float* b_obj2 = (const float*)d_in[6];
  // d_in[7]=W_ah, d_in[8]=W_ac: dead (softmax over size-1 axis == 1)
  const float* W_ih0  = (const float*)d_in[9];
  const float* W_hh0  = (const float*)d_in[10];
  const float* b_ih0  = (const float*)d_in[11];
  const float* b_hh0  = (const float*)d_in[12];
  const float* W_ih1  = (const float*)d_in[13];
  const float* W_hh1  = (const float*)d_in[14];
  const float* b_ih1  = (const float*)d_in[15];
  const float* b_hh1  = (const float*)d_in[16];
  const float* W_out  = (const float*)d_in[17];
  const float* b_out  = (const float*)d_in[18];

  float* out    = (float*)d_out;
  float* alphas = out;            // 60800
  float* preds  = out + 60800;    // 3200

  float* ws     = (float*)d_ws;
  float* z      = ws;                     // 13107200 (dead after zW GEMM)
  float* Wpk0   = z;                      // 1048576  (packed after zW GEMM)
  float* Wpk1   = z + 1048576;            // 2097152
  float* zW     = z + 13107200;           // 1638400
  float* xl     = zW + 1638400;           // 3276800
  float* gin    = xl + 3276800;           // 6553600
  float* s1     = gin + 6553600;          // 3200
  float* s2     = s1 + 3200;              // 3200
  float* vb     = s2 + 3200;              // 512
  float* h0_all = vb + 512;               // 1638400  (100 x 32 x 512)
  float* h1_all = h0_all + 1638400;       // 1638400
  float* c0_st  = h1_all + 1638400;       // 16384
  float* c1_st  = c0_st + 16384;          // 16384

  // cell states must start at zero every call (incl. graph replays)
  hipMemsetAsync(c0_st, 0, 2 * 16384 * sizeof(float), stream);

  mask_z_kernel<<<3200, 256, 0, stream>>>(x, z, s1, s2, alphas);
  colvec_kernel<<<2, 256, 0, stream>>>(W_obj2, b_obj, vb);
  // img_feat = x[:,:,0,:] @ W_img^T + b_img  -> xl[:, 0:512]
  gemm_atb<<<dim3(50, 8), 256, 0, stream>>>(x, 81920, W_img, 4096, xl, 1024,
      b_img, nullptr, nullptr, nullptr, nullptr, nullptr);
  // zW = z @ W_obj^T
  gemm_atb<<<dim3(50, 8), 256, 0, stream>>>(z, 4096, W_obj, 4096, zW, 512,
      nullptr, nullptr, nullptr, nullptr, nullptr, nullptr);
  // z is now dead: pack weights K-major into it
  pack_w<<<3072, 256, 0, stream>>>(W_hh0, W_ih1, W_hh1, Wpk0, Wpk1);
  // w_obj = zW @ W_obj2^T + s2*vb + s1*b_obj2 -> xl[:, 512:1024]
  gemm_atb<<<dim3(50, 8), 256, 0, stream>>>(zW, 512, W_obj2, 512, xl + 512, 1024,
      nullptr, nullptr, s2, vb, s1, b_obj2);
  // gin = xl @ W_ih0^T + b_ih0 + b_hh0
  gemm_atb<<<dim3(50, 32), 256, 0, stream>>>(xl, 1024, W_ih0, 1024, gin, 2048,
      b_ih0, b_hh0, nullptr, nullptr, nullptr, nullptr);

  // Recurrence: 102 lean phase launches (L0[p] || L1[p-1] || pred[p-2])
  for (int p = 0; p <= 101; ++p) {
    lstm_phase2<<<256, 512, 0, stream>>>(gin, Wpk0, Wpk1, b_ih1, b_hh1,
        W_out, b_out, h0_all, h1_all, c0_st, c1_st, preds, p);
  }
}